// Round 5
// baseline (25389.615 us; speedup 1.0000x reference)
//
#include <hip/hip_runtime.h>
#include <math.h>

#define T_ 512

__device__ __forceinline__ float sigm(float x)  { return 1.0f / (1.0f + __expf(-x)); }
__device__ __forceinline__ float tanhf_(float x){ return 1.0f - 2.0f / (1.0f + __expf(2.0f * x)); }

// ---------------------------------------------------------------------------
// prep 1: AT[j*128+i] = A[i*128+j] ; in_wT[c*16+k] = in_w[k*96+c]
// grid = 70 x 256 = 17920 = 16384 + 1536 exactly
// ---------------------------------------------------------------------------
__global__ __launch_bounds__(256) void k_prep(const float* __restrict__ A,
                                              const float* __restrict__ in_w,
                                              float* __restrict__ AT,
                                              float* __restrict__ in_wT)
{
    int idx = blockIdx.x * 256 + threadIdx.x;
    if (idx < 16384) {
        int j = idx >> 7, i = idx & 127;
        AT[idx] = A[i * 128 + j];
    } else {
        int e = idx - 16384;          // e = c*16 + k
        int c = e >> 4, k = e & 15;
        in_wT[e] = in_w[k * 96 + c];
    }
}

// ---------------------------------------------------------------------------
// prep 2: per-row projections  xa[p] = X[p]@in_w[:,0:32]+in_b[0:32],
//                              xb[p] = X[p]@in_w[:,32:64]+in_b[32:64]
// (flat row p is the SAME for both coordinate systems — raw reshape)
// ---------------------------------------------------------------------------
__global__ __launch_bounds__(256) void k_pre(const float* __restrict__ X,
                                             const float* __restrict__ w,
                                             const float* __restrict__ b,
                                             float* __restrict__ xa,
                                             float* __restrict__ xb)
{
    int p = blockIdx.x * 256 + threadIdx.x;
    float x[16];
    const float4* xr = (const float4*)(X + (size_t)p * 16);
#pragma unroll
    for (int k = 0; k < 4; ++k) {
        float4 v = xr[k];
        x[4*k+0] = v.x; x[4*k+1] = v.y; x[4*k+2] = v.z; x[4*k+3] = v.w;
    }
    float* outs[2] = { xa, xb };
#pragma unroll
    for (int g = 0; g < 2; ++g) {
        float acc[32];
#pragma unroll
        for (int j = 0; j < 32; ++j) acc[j] = b[g*32 + j];
#pragma unroll
        for (int k = 0; k < 16; ++k) {
            float xv = x[k];
#pragma unroll
            for (int j = 0; j < 32; ++j)
                acc[j] = fmaf(xv, w[k*96 + g*32 + j], acc[j]);
        }
        float4* o = (float4*)(outs[g] + (size_t)p * 32);
#pragma unroll
        for (int q = 0; q < 8; ++q)
            o[q] = make_float4(acc[4*q], acc[4*q+1], acc[4*q+2], acc[4*q+3]);
    }
}

// ---------------------------------------------------------------------------
// Fused net: one block per (b,t). xres in LDS, skip in registers.
// Thread (i = tid&127, fh = tid>>7) owns node i, channel half [fh*16, fh*16+16).
// Conv path reads xa/xb at flat rows q0=(b*128+i)*512+t and q0-d (reshape coords);
// xres path uses true coords (flat row btid*128+i).
// ---------------------------------------------------------------------------
__global__ __launch_bounds__(256) void k_fused(
    const float* __restrict__ X,
    const float* __restrict__ xa,
    const float* __restrict__ xb,
    const float* __restrict__ AT,
    const float* __restrict__ in_wT,
    const float* __restrict__ in_b,
    const float* __restrict__ ct_w,  const float* __restrict__ ct_b,
    const float* __restrict__ cs_w,  const float* __restrict__ cs_b,
    const float* __restrict__ gcn_w, const float* __restrict__ gcn_b,
    const float* __restrict__ res_w, const float* __restrict__ res_b,
    const float* __restrict__ skip_w,const float* __restrict__ skip_b,
    const float* __restrict__ w1,    const float* __restrict__ b1,
    const float* __restrict__ w2,    const float* __restrict__ b2,
    float* __restrict__ out)
{
    __shared__ float xs[128 * 36];   // xres state tile (stride 36: conflict-free updates)
    __shared__ float hs[128 * 36];   // Ax / h / head exchange

    const int btid = blockIdx.x;           // b*512 + t
    const int b = btid >> 9, t = btid & (T_ - 1);
    const int tid = threadIdx.x;
    const int i = tid & 127;
    const int fh = tid >> 7;               // wave-uniform
    const int fh16 = fh * 16;

    const size_t q0 = (size_t)(b * 128 + i) * T_ + t;   // reshape-coordinate row

    // ---- init xres half into LDS from TRUE-coordinate X row ----
    {
        float Xr[16];
        const float4* r4 = (const float4*)(X + ((size_t)btid * 128 + i) * 16);
#pragma unroll
        for (int k = 0; k < 4; ++k) {
            float4 v = r4[k];
            Xr[4*k+0] = v.x; Xr[4*k+1] = v.y; Xr[4*k+2] = v.z; Xr[4*k+3] = v.w;
        }
        float4* xrow = (float4*)(xs + i * 36 + fh16);
#pragma unroll
        for (int q = 0; q < 4; ++q) {
            float v[4];
#pragma unroll
            for (int u = 0; u < 4; ++u) {
                int c = fh16 + q * 4 + u;
                float a = in_b[64 + c];
                const float4* wr = (const float4*)(in_wT + (64 + c) * 16);
#pragma unroll
                for (int k4 = 0; k4 < 4; ++k4) {
                    float4 w = wr[k4];
                    a = fmaf(Xr[4*k4+0], w.x, a);
                    a = fmaf(Xr[4*k4+1], w.y, a);
                    a = fmaf(Xr[4*k4+2], w.z, a);
                    a = fmaf(Xr[4*k4+3], w.w, a);
                }
                v[u] = a;
            }
            xrow[q] = make_float4(v[0], v[1], v[2], v[3]);
        }
    }

    float sk[16];                    // skip accumulator (registers, all layers)
#pragma unroll
    for (int q = 0; q < 16; ++q) sk[q] = 0.f;

    __syncthreads();                 // xs tile ready

#pragma unroll 1
    for (int l = 0; l < 4; ++l) {
        const int d = 1 << l;
        const bool pv = (t >= d);    // block-uniform causal validity
        const float* wt  = ct_w + l * 2048;  const float* btc = ct_b + l * 32;
        const float* wsg = cs_w + l * 2048;  const float* bsc = cs_b + l * 32;
        const float* gw  = gcn_w + l * 1024; const float* gb  = gcn_b + l * 32;
        const float* rw  = res_w + l * 1024; const float* rb  = res_b + l * 32;
        const float* sw  = skip_w + l * 1024;const float* sb  = skip_b + l * 32;

        // ---- gated causal conv from precomputed xa/xb rows, 4-ci chunks ----
        float g[16], ac[16];
#pragma unroll
        for (int co = 0; co < 16; ++co) g[co] = btc[fh16 + co];
        {
            const float4* c4 = (const float4*)(xa + q0 * 32);
            const float4* p4 = (const float4*)(xa + (q0 - (size_t)d) * 32);
#pragma unroll
            for (int k4 = 0; k4 < 8; ++k4) {
                float4 cv = c4[k4];
                float4 pw = pv ? p4[k4] : make_float4(0.f, 0.f, 0.f, 0.f);
                float cs_[4] = { cv.x, cv.y, cv.z, cv.w };
                float ps_[4] = { pw.x, pw.y, pw.z, pw.w };
#pragma unroll
                for (int u = 0; u < 4; ++u) {
                    int ci = k4 * 4 + u;
                    const float4* w0 = (const float4*)(wt + ci * 32 + fh16);          // tap0 (prev)
                    const float4* w1 = (const float4*)(wt + 1024 + ci * 32 + fh16);   // tap1 (cur)
#pragma unroll
                    for (int q = 0; q < 4; ++q) {
                        float4 a0 = w0[q], a1 = w1[q];
                        g[4*q+0] = fmaf(ps_[u], a0.x, fmaf(cs_[u], a1.x, g[4*q+0]));
                        g[4*q+1] = fmaf(ps_[u], a0.y, fmaf(cs_[u], a1.y, g[4*q+1]));
                        g[4*q+2] = fmaf(ps_[u], a0.z, fmaf(cs_[u], a1.z, g[4*q+2]));
                        g[4*q+3] = fmaf(ps_[u], a0.w, fmaf(cs_[u], a1.w, g[4*q+3]));
                    }
                }
            }
        }
#pragma unroll
        for (int co = 0; co < 16; ++co) ac[co] = bsc[fh16 + co];
        {
            const float4* c4 = (const float4*)(xb + q0 * 32);
            const float4* p4 = (const float4*)(xb + (q0 - (size_t)d) * 32);
#pragma unroll
            for (int k4 = 0; k4 < 8; ++k4) {
                float4 cv = c4[k4];
                float4 pw = pv ? p4[k4] : make_float4(0.f, 0.f, 0.f, 0.f);
                float cs_[4] = { cv.x, cv.y, cv.z, cv.w };
                float ps_[4] = { pw.x, pw.y, pw.z, pw.w };
#pragma unroll
                for (int u = 0; u < 4; ++u) {
                    int ci = k4 * 4 + u;
                    const float4* w0 = (const float4*)(wsg + ci * 32 + fh16);
                    const float4* w1 = (const float4*)(wsg + 1024 + ci * 32 + fh16);
#pragma unroll
                    for (int q = 0; q < 4; ++q) {
                        float4 a0 = w0[q], a1 = w1[q];
                        ac[4*q+0] = fmaf(ps_[u], a0.x, fmaf(cs_[u], a1.x, ac[4*q+0]));
                        ac[4*q+1] = fmaf(ps_[u], a0.y, fmaf(cs_[u], a1.y, ac[4*q+1]));
                        ac[4*q+2] = fmaf(ps_[u], a0.z, fmaf(cs_[u], a1.z, ac[4*q+2]));
                        ac[4*q+3] = fmaf(ps_[u], a0.w, fmaf(cs_[u], a1.w, ac[4*q+3]));
                    }
                }
            }
        }
#pragma unroll
        for (int co = 0; co < 16; ++co)
            g[co] = tanhf_(g[co]) * sigm(ac[co]);   // g now holds tc

        // ---- A-mix: acc = sum_j A[i,j] * xs[j, fh-half] ----
        float acc[16];
#pragma unroll
        for (int q = 0; q < 16; ++q) acc[q] = 0.f;
        const float* ATp = AT + i;
#pragma unroll 2
        for (int j = 0; j < 128; ++j) {
            float a = ATp[j << 7];                                   // lane-coalesced
            const float4* xr = (const float4*)(xs + j * 36 + fh16);  // broadcast
#pragma unroll
            for (int q = 0; q < 4; ++q) {
                float4 v = xr[q];
                acc[4*q+0] = fmaf(a, v.x, acc[4*q+0]);
                acc[4*q+1] = fmaf(a, v.y, acc[4*q+1]);
                acc[4*q+2] = fmaf(a, v.z, acc[4*q+2]);
                acc[4*q+3] = fmaf(a, v.w, acc[4*q+3]);
            }
        }
        {
            float4* hrow = (float4*)(hs + i * 36 + fh16);
#pragma unroll
            for (int q = 0; q < 4; ++q)
                hrow[q] = make_float4(acc[4*q], acc[4*q+1], acc[4*q+2], acc[4*q+3]);
        }
        __syncthreads();   // (a) Ax ready

        // ---- gcn: h = Ax_row @ gw + gb ; h += tc ----
        float h[16];
#pragma unroll
        for (int q = 0; q < 16; ++q) h[q] = gb[fh16 + q];
        {
            const float4* arow = (const float4*)(hs + i * 36);
#pragma unroll 2
            for (int f4 = 0; f4 < 8; ++f4) {
                float4 av = arow[f4];
                float avs[4] = { av.x, av.y, av.z, av.w };
#pragma unroll
                for (int u = 0; u < 4; ++u) {
                    float a = avs[u];
                    const float4* w4 = (const float4*)(gw + (f4*4+u) * 32 + fh16);
#pragma unroll
                    for (int q = 0; q < 4; ++q) {
                        float4 w = w4[q];
                        h[4*q+0] = fmaf(a, w.x, h[4*q+0]);
                        h[4*q+1] = fmaf(a, w.y, h[4*q+1]);
                        h[4*q+2] = fmaf(a, w.z, h[4*q+2]);
                        h[4*q+3] = fmaf(a, w.w, h[4*q+3]);
                    }
                }
            }
        }
#pragma unroll
        for (int q = 0; q < 16; ++q) h[q] += g[q];

        __syncthreads();   // (b) all Ax reads done
        {
            float4* hrow = (float4*)(hs + i * 36 + fh16);
#pragma unroll
            for (int q = 0; q < 4; ++q)
                hrow[q] = make_float4(h[4*q], h[4*q+1], h[4*q+2], h[4*q+3]);
        }
        __syncthreads();   // (c) h ready

        // ---- res & skip mixes from full h row ----
        float r[16];
#pragma unroll
        for (int q = 0; q < 16; ++q) { r[q] = rb[fh16 + q]; sk[q] += sb[fh16 + q]; }
        {
            const float4* hrow = (const float4*)(hs + i * 36);
#pragma unroll 2
            for (int f4 = 0; f4 < 8; ++f4) {
                float4 hv = hrow[f4];
                float hvs[4] = { hv.x, hv.y, hv.z, hv.w };
#pragma unroll
                for (int u = 0; u < 4; ++u) {
                    float a = hvs[u];
                    const float4* rw4 = (const float4*)(rw + (f4*4+u) * 32 + fh16);
                    const float4* sw4 = (const float4*)(sw + (f4*4+u) * 32 + fh16);
#pragma unroll
                    for (int q = 0; q < 4; ++q) {
                        float4 wR = rw4[q], wS = sw4[q];
                        r[4*q+0] = fmaf(a, wR.x, r[4*q+0]);
                        r[4*q+1] = fmaf(a, wR.y, r[4*q+1]);
                        r[4*q+2] = fmaf(a, wR.z, r[4*q+2]);
                        r[4*q+3] = fmaf(a, wR.w, r[4*q+3]);
                        sk[4*q+0] = fmaf(a, wS.x, sk[4*q+0]);
                        sk[4*q+1] = fmaf(a, wS.y, sk[4*q+1]);
                        sk[4*q+2] = fmaf(a, wS.z, sk[4*q+2]);
                        sk[4*q+3] = fmaf(a, wS.w, sk[4*q+3]);
                    }
                }
            }
        }
        // xres update (exclusive half-row per thread)
        {
            float* xrow = xs + i * 36 + fh16;
#pragma unroll
            for (int q = 0; q < 16; ++q) xrow[q] += r[q];
        }
        __syncthreads();   // (d) xs updated, hs reads done
    }

    // ---- output head ----
    {
        float4* srow = (float4*)(hs + i * 36 + fh16);
#pragma unroll
        for (int q = 0; q < 4; ++q)
            srow[q] = make_float4(fmaxf(sk[4*q+0], 0.f), fmaxf(sk[4*q+1], 0.f),
                                  fmaxf(sk[4*q+2], 0.f), fmaxf(sk[4*q+3], 0.f));
    }
    __syncthreads();

    float h1[16];
#pragma unroll
    for (int q = 0; q < 16; ++q) h1[q] = b1[fh16 + q];
    {
        const float4* srow = (const float4*)(hs + i * 36);
#pragma unroll 2
        for (int f4 = 0; f4 < 8; ++f4) {
            float4 sv = srow[f4];
            float svs[4] = { sv.x, sv.y, sv.z, sv.w };
#pragma unroll
            for (int u = 0; u < 4; ++u) {
                float a = svs[u];
                const float4* w4 = (const float4*)(w1 + (f4*4+u) * 32 + fh16);
#pragma unroll
                for (int q = 0; q < 4; ++q) {
                    float4 w = w4[q];
                    h1[4*q+0] = fmaf(a, w.x, h1[4*q+0]);
                    h1[4*q+1] = fmaf(a, w.y, h1[4*q+1]);
                    h1[4*q+2] = fmaf(a, w.z, h1[4*q+2]);
                    h1[4*q+3] = fmaf(a, w.w, h1[4*q+3]);
                }
            }
        }
    }
    __syncthreads();   // done reading relu(skip)
    {
        float4* hrow = (float4*)(hs + i * 36 + fh16);
#pragma unroll
        for (int q = 0; q < 4; ++q)
            hrow[q] = make_float4(fmaxf(h1[4*q+0], 0.f), fmaxf(h1[4*q+1], 0.f),
                                  fmaxf(h1[4*q+2], 0.f), fmaxf(h1[4*q+3], 0.f));
    }
    __syncthreads();

    const int fh8 = fh * 8;
    float o[8];
#pragma unroll
    for (int q = 0; q < 8; ++q) o[q] = b2[fh8 + q];
    {
        const float4* hrow = (const float4*)(hs + i * 36);
#pragma unroll 2
        for (int f4 = 0; f4 < 8; ++f4) {
            float4 hv = hrow[f4];
            float hvs[4] = { hv.x, hv.y, hv.z, hv.w };
#pragma unroll
            for (int u = 0; u < 4; ++u) {
                float a = hvs[u];
                const float4* w4 = (const float4*)(w2 + (f4*4+u) * 16 + fh8);
#pragma unroll
                for (int q = 0; q < 2; ++q) {
                    float4 w = w4[q];
                    o[4*q+0] = fmaf(a, w.x, o[4*q+0]);
                    o[4*q+1] = fmaf(a, w.y, o[4*q+1]);
                    o[4*q+2] = fmaf(a, w.z, o[4*q+2]);
                    o[4*q+3] = fmaf(a, w.w, o[4*q+3]);
                }
            }
        }
    }
    {
        float4* og = (float4*)(out + ((size_t)btid * 128 + i) * 16 + fh8);
        og[0] = make_float4(o[0], o[1], o[2], o[3]);
        og[1] = make_float4(o[4], o[5], o[6], o[7]);
    }
}

// ---------------------------------------------------------------------------
extern "C" void kernel_launch(void* const* d_in, const int* in_sizes, int n_in,
                              void* d_out, int out_size, void* d_ws, size_t ws_size,
                              hipStream_t stream)
{
    const float* X      = (const float*)d_in[0];
    const float* A      = (const float*)d_in[1];
    const float* in_w   = (const float*)d_in[2];
    const float* in_b   = (const float*)d_in[3];
    const float* ct_w   = (const float*)d_in[4];
    const float* ct_b   = (const float*)d_in[5];
    const float* cs_w   = (const float*)d_in[6];
    const float* cs_b   = (const float*)d_in[7];
    const float* gcn_w  = (const float*)d_in[8];
    const float* gcn_b  = (const float*)d_in[9];
    const float* res_w  = (const float*)d_in[10];
    const float* res_b  = (const float*)d_in[11];
    const float* skip_w = (const float*)d_in[12];
    const float* skip_b = (const float*)d_in[13];
    const float* out1_w = (const float*)d_in[14];
    const float* out1_b = (const float*)d_in[15];
    const float* out2_w = (const float*)d_in[16];
    const float* out2_b = (const float*)d_in[17];

    float* ws = (float*)d_ws;
    const size_t SZ = (size_t)524288 * 32;    // 16.78M floats per projection buffer
    float* AT    = ws;                         // 16384 floats
    float* in_wT = ws + 16384;                 // 1536 floats
    float* xa    = ws + 18432;                 // 67.1 MB
    float* xb    = xa + SZ;                    // 67.1 MB   (total ~134.3 MB)

    k_prep<<<70, 256, 0, stream>>>(A, in_w, AT, in_wT);
    k_pre <<<2048, 256, 0, stream>>>(X, in_w, in_b, xa, xb);

    k_fused<<<8 * T_, 256, 0, stream>>>(X, xa, xb, AT, in_wT, in_b,
                                        ct_w, ct_b, cs_w, cs_b,
                                        gcn_w, gcn_b, res_w, res_b,
                                        skip_w, skip_b,
                                        out1_w, out1_b, out2_w, out2_b,
                                        (float*)d_out);
}

// Round 6
// 2406.796 us; speedup vs baseline: 10.5491x; 10.5491x over previous
//
#include <hip/hip_runtime.h>
#include <math.h>

#define T_ 512

__device__ __forceinline__ float sigm(float x)  { return 1.0f / (1.0f + __expf(-x)); }
__device__ __forceinline__ float tanhf_(float x){ return 1.0f - 2.0f / (1.0f + __expf(2.0f * x)); }

// ---------------------------------------------------------------------------
// prep 1: AT[j*128+i] = A[i*128+j] ; in_wT[c*16+k] = in_w[k*96+c]
// ---------------------------------------------------------------------------
__global__ __launch_bounds__(256) void k_prep(const float* __restrict__ A,
                                              const float* __restrict__ in_w,
                                              float* __restrict__ AT,
                                              float* __restrict__ in_wT)
{
    int idx = blockIdx.x * 256 + threadIdx.x;
    if (idx < 16384) {
        int j = idx >> 7, i = idx & 127;
        AT[idx] = A[i * 128 + j];
    } else {
        int e = idx - 16384;          // e = c*16 + k
        int c = e >> 4, k = e & 15;
        in_wT[e] = in_w[k * 96 + c];
    }
}

// ---------------------------------------------------------------------------
// prep 2: xa[p] = X[p]@in_w[:,0:32]+in_b[0:32], xb[p] = X[p]@in_w[:,32:64]+in_b[32:64]
// ---------------------------------------------------------------------------
__global__ __launch_bounds__(256) void k_pre(const float* __restrict__ X,
                                             const float* __restrict__ w,
                                             const float* __restrict__ b,
                                             float* __restrict__ xa,
                                             float* __restrict__ xb)
{
    int p = blockIdx.x * 256 + threadIdx.x;
    float x[16];
    const float4* xr = (const float4*)(X + (size_t)p * 16);
#pragma unroll
    for (int k = 0; k < 4; ++k) {
        float4 v = xr[k];
        x[4*k+0] = v.x; x[4*k+1] = v.y; x[4*k+2] = v.z; x[4*k+3] = v.w;
    }
    float* outs[2] = { xa, xb };
#pragma unroll
    for (int g = 0; g < 2; ++g) {
        float acc[32];
#pragma unroll
        for (int j = 0; j < 32; ++j) acc[j] = b[g*32 + j];
#pragma unroll
        for (int k = 0; k < 16; ++k) {
            float xv = x[k];
#pragma unroll
            for (int j = 0; j < 32; ++j)
                acc[j] = fmaf(xv, w[k*96 + g*32 + j], acc[j]);
        }
        float4* o = (float4*)(outs[g] + (size_t)p * 32);
#pragma unroll
        for (int q = 0; q < 8; ++q)
            o[q] = make_float4(acc[4*q], acc[4*q+1], acc[4*q+2], acc[4*q+3]);
    }
}

// ---------------------------------------------------------------------------
// Fused net: one block per (b,t). xres in LDS, skip in registers.
// Thread (i = tid&127, fh = tid>>7) owns node i, channel half [fh*16, fh*16+16).
// ALL weight/bias pointers are rebased via readfirstlane(fh16) so the compiler
// proves uniformity and emits s_load -> SGPR + v_fma(v,s,v): weights never
// touch VGPRs or the vector memory pipe.
// ---------------------------------------------------------------------------
__global__ __launch_bounds__(256, 3) void k_fused(
    const float* __restrict__ X,
    const float* __restrict__ xa,
    const float* __restrict__ xb,
    const float* __restrict__ AT,
    const float* __restrict__ in_wT,
    const float* __restrict__ in_b,
    const float* __restrict__ ct_w,  const float* __restrict__ ct_b,
    const float* __restrict__ cs_w,  const float* __restrict__ cs_b,
    const float* __restrict__ gcn_w, const float* __restrict__ gcn_b,
    const float* __restrict__ res_w, const float* __restrict__ res_b,
    const float* __restrict__ skip_w,const float* __restrict__ skip_b,
    const float* __restrict__ w1,    const float* __restrict__ b1,
    const float* __restrict__ w2,    const float* __restrict__ b2,
    float* __restrict__ out)
{
    __shared__ float xs[128 * 36];   // xres state (stride 36: measured 0 conflicts)
    __shared__ float hs[128 * 36];   // Ax / h / head exchange

    const int btid = blockIdx.x;           // b*512 + t
    const int b = btid >> 9, t = btid & (T_ - 1);
    const int tid = threadIdx.x;
    const int i = tid & 127;
    const int fh = tid >> 7;
    const int ufh  = __builtin_amdgcn_readfirstlane(fh * 16);  // wave-uniform half base
    const int ufh8 = __builtin_amdgcn_readfirstlane(fh * 8);

    const size_t q0 = (size_t)(b * 128 + i) * T_ + t;   // reshape-coordinate row

    // ---- init xres half into LDS from TRUE-coordinate X row ----
    {
        float Xr[16];
        const float4* r4 = (const float4*)(X + ((size_t)btid * 128 + i) * 16);
#pragma unroll
        for (int k = 0; k < 4; ++k) {
            float4 v = r4[k];
            Xr[4*k+0] = v.x; Xr[4*k+1] = v.y; Xr[4*k+2] = v.z; Xr[4*k+3] = v.w;
        }
        const float* wT_u = in_wT + (64 + ufh) * 16;   // uniform
        const float* ib_u = in_b + 64 + ufh;           // uniform
        float* xrow = xs + i * 36 + ufh;
#pragma unroll
        for (int c = 0; c < 16; ++c) {
            float a = ib_u[c];
#pragma unroll
            for (int k = 0; k < 16; ++k)
                a = fmaf(Xr[k], wT_u[c * 16 + k], a);
            xrow[c] = a;
        }
    }

    float sk[16];                    // skip accumulator (registers, all layers)
#pragma unroll
    for (int q = 0; q < 16; ++q) sk[q] = 0.f;

    __syncthreads();                 // xs tile ready

#pragma unroll 1
    for (int l = 0; l < 4; ++l) {
        const int d = 1 << l;
        const bool pv = (t >= d);    // block-uniform causal validity
        // uniform (scalar-pipe) weight bases for this layer + half
        const float* wt_u = ct_w  + l * 2048 + ufh;
        const float* ws_u = cs_w  + l * 2048 + ufh;
        const float* gw_u = gcn_w + l * 1024 + ufh;
        const float* rw_u = res_w + l * 1024 + ufh;
        const float* sw_u = skip_w+ l * 1024 + ufh;
        const float* bt_u = ct_b  + l * 32 + ufh;
        const float* bs_u = cs_b  + l * 32 + ufh;
        const float* gb_u = gcn_b + l * 32 + ufh;
        const float* rb_u = res_b + l * 32 + ufh;
        const float* sb_u = skip_b+ l * 32 + ufh;

        const size_t qp = pv ? (q0 - (size_t)d) : q0;   // clamped: always valid

        // ---- gated causal conv from precomputed xa/xb rows ----
        float g[16];
#pragma unroll
        for (int co = 0; co < 16; ++co) g[co] = bt_u[co];
        {
            const float4* c4 = (const float4*)(xa + q0 * 32);
            const float4* p4 = (const float4*)(xa + qp * 32);
#pragma unroll
            for (int k4 = 0; k4 < 8; ++k4) {
                float4 cv = c4[k4];
                float4 pw = pv ? p4[k4] : make_float4(0.f, 0.f, 0.f, 0.f);
                float cc[4] = { cv.x, cv.y, cv.z, cv.w };
                float pp[4] = { pw.x, pw.y, pw.z, pw.w };
#pragma unroll
                for (int u = 0; u < 4; ++u) {
                    const int ci = k4 * 4 + u;
                    const float a0 = pp[u], a1 = cc[u];
#pragma unroll
                    for (int co = 0; co < 16; ++co)
                        g[co] = fmaf(a0, wt_u[ci * 32 + co],
                                fmaf(a1, wt_u[1024 + ci * 32 + co], g[co]));
                }
            }
        }
        float ac[16];
#pragma unroll
        for (int co = 0; co < 16; ++co) ac[co] = bs_u[co];
        {
            const float4* c4 = (const float4*)(xb + q0 * 32);
            const float4* p4 = (const float4*)(xb + qp * 32);
#pragma unroll
            for (int k4 = 0; k4 < 8; ++k4) {
                float4 cv = c4[k4];
                float4 pw = pv ? p4[k4] : make_float4(0.f, 0.f, 0.f, 0.f);
                float cc[4] = { cv.x, cv.y, cv.z, cv.w };
                float pp[4] = { pw.x, pw.y, pw.z, pw.w };
#pragma unroll
                for (int u = 0; u < 4; ++u) {
                    const int ci = k4 * 4 + u;
                    const float a0 = pp[u], a1 = cc[u];
#pragma unroll
                    for (int co = 0; co < 16; ++co)
                        ac[co] = fmaf(a0, ws_u[ci * 32 + co],
                                 fmaf(a1, ws_u[1024 + ci * 32 + co], ac[co]));
                }
            }
        }
#pragma unroll
        for (int co = 0; co < 16; ++co)
            g[co] = tanhf_(g[co]) * sigm(ac[co]);   // g now holds tc

        // ---- A-mix: acc = sum_j A[i,j] * xs[j, fh-half] ----
        float acc[16];
#pragma unroll
        for (int q = 0; q < 16; ++q) acc[q] = 0.f;
        const float* ATp = AT + i;
#pragma unroll 2
        for (int j = 0; j < 128; ++j) {
            float a = ATp[j << 7];                                   // lane-coalesced
            const float4* xr = (const float4*)(xs + j * 36 + ufh);   // uniform -> broadcast
#pragma unroll
            for (int q = 0; q < 4; ++q) {
                float4 v = xr[q];
                acc[4*q+0] = fmaf(a, v.x, acc[4*q+0]);
                acc[4*q+1] = fmaf(a, v.y, acc[4*q+1]);
                acc[4*q+2] = fmaf(a, v.z, acc[4*q+2]);
                acc[4*q+3] = fmaf(a, v.w, acc[4*q+3]);
            }
        }
        {
            float4* hrow = (float4*)(hs + i * 36 + ufh);
#pragma unroll
            for (int q = 0; q < 4; ++q)
                hrow[q] = make_float4(acc[4*q], acc[4*q+1], acc[4*q+2], acc[4*q+3]);
        }
        __syncthreads();   // (a) Ax ready

        // ---- gcn: h = Ax_row @ gw + gb ; h += tc ----
        float h[16];
#pragma unroll
        for (int q = 0; q < 16; ++q) h[q] = gb_u[q];
        {
            const float4* arow = (const float4*)(hs + i * 36);
#pragma unroll 2
            for (int f4 = 0; f4 < 8; ++f4) {
                float4 av = arow[f4];
                float avs[4] = { av.x, av.y, av.z, av.w };
#pragma unroll
                for (int u = 0; u < 4; ++u) {
                    const float a = avs[u];
#pragma unroll
                    for (int q = 0; q < 16; ++q)
                        h[q] = fmaf(a, gw_u[(f4 * 4 + u) * 32 + q], h[q]);
                }
            }
        }
#pragma unroll
        for (int q = 0; q < 16; ++q) h[q] += g[q];

        __syncthreads();   // (b) all Ax reads done
        {
            float4* hrow = (float4*)(hs + i * 36 + ufh);
#pragma unroll
            for (int q = 0; q < 4; ++q)
                hrow[q] = make_float4(h[4*q], h[4*q+1], h[4*q+2], h[4*q+3]);
        }
        __syncthreads();   // (c) h ready

        // ---- res & skip mixes from full h row ----
        float r[16];
#pragma unroll
        for (int q = 0; q < 16; ++q) { r[q] = rb_u[q]; sk[q] += sb_u[q]; }
        {
            const float4* hrow = (const float4*)(hs + i * 36);
#pragma unroll 2
            for (int f4 = 0; f4 < 8; ++f4) {
                float4 hv = hrow[f4];
                float hvs[4] = { hv.x, hv.y, hv.z, hv.w };
#pragma unroll
                for (int u = 0; u < 4; ++u) {
                    const float a = hvs[u];
                    const int f = f4 * 4 + u;
#pragma unroll
                    for (int q = 0; q < 16; ++q) {
                        r[q]  = fmaf(a, rw_u[f * 32 + q], r[q]);
                        sk[q] = fmaf(a, sw_u[f * 32 + q], sk[q]);
                    }
                }
            }
        }
        // xres update (exclusive half-row per thread)
        {
            float* xrow = xs + i * 36 + ufh;
#pragma unroll
            for (int q = 0; q < 16; ++q) xrow[q] += r[q];
        }
        __syncthreads();   // (d) xs updated, hs reads done
    }

    // ---- output head ----
    {
        float* srow = hs + i * 36 + ufh;
#pragma unroll
        for (int q = 0; q < 16; ++q) srow[q] = fmaxf(sk[q], 0.f);
    }
    __syncthreads();

    const float* b1_u = b1 + ufh;
    const float* w1_u = w1 + ufh;
    float h1[16];
#pragma unroll
    for (int q = 0; q < 16; ++q) h1[q] = b1_u[q];
    {
        const float4* srow = (const float4*)(hs + i * 36);
#pragma unroll 2
        for (int f4 = 0; f4 < 8; ++f4) {
            float4 sv = srow[f4];
            float svs[4] = { sv.x, sv.y, sv.z, sv.w };
#pragma unroll
            for (int u = 0; u < 4; ++u) {
                const float a = svs[u];
#pragma unroll
                for (int q = 0; q < 16; ++q)
                    h1[q] = fmaf(a, w1_u[(f4 * 4 + u) * 32 + q], h1[q]);
            }
        }
    }
    __syncthreads();   // done reading relu(skip)
    {
        float* hrow = hs + i * 36 + ufh;
#pragma unroll
        for (int q = 0; q < 16; ++q) hrow[q] = fmaxf(h1[q], 0.f);
    }
    __syncthreads();

    const float* b2_u = b2 + ufh8;
    const float* w2_u = w2 + ufh8;
    float o[8];
#pragma unroll
    for (int q = 0; q < 8; ++q) o[q] = b2_u[q];
    {
        const float4* hrow = (const float4*)(hs + i * 36);
#pragma unroll 2
        for (int f4 = 0; f4 < 8; ++f4) {
            float4 hv = hrow[f4];
            float hvs[4] = { hv.x, hv.y, hv.z, hv.w };
#pragma unroll
            for (int u = 0; u < 4; ++u) {
                const float a = hvs[u];
#pragma unroll
                for (int q = 0; q < 8; ++q)
                    o[q] = fmaf(a, w2_u[(f4 * 4 + u) * 16 + q], o[q]);
            }
        }
    }
    {
        float4* og = (float4*)(out + ((size_t)btid * 128 + i) * 16 + ufh8);
        og[0] = make_float4(o[0], o[1], o[2], o[3]);
        og[1] = make_float4(o[4], o[5], o[6], o[7]);
    }
}

// ---------------------------------------------------------------------------
extern "C" void kernel_launch(void* const* d_in, const int* in_sizes, int n_in,
                              void* d_out, int out_size, void* d_ws, size_t ws_size,
                              hipStream_t stream)
{
    const float* X      = (const float*)d_in[0];
    const float* A      = (const float*)d_in[1];
    const float* in_w   = (const float*)d_in[2];
    const float* in_b   = (const float*)d_in[3];
    const float* ct_w   = (const float*)d_in[4];
    const float* ct_b   = (const float*)d_in[5];
    const float* cs_w   = (const float*)d_in[6];
    const float* cs_b   = (const float*)d_in[7];
    const float* gcn_w  = (const float*)d_in[8];
    const float* gcn_b  = (const float*)d_in[9];
    const float* res_w  = (const float*)d_in[10];
    const float* res_b  = (const float*)d_in[11];
    const float* skip_w = (const float*)d_in[12];
    const float* skip_b = (const float*)d_in[13];
    const float* out1_w = (const float*)d_in[14];
    const float* out1_b = (const float*)d_in[15];
    const float* out2_w = (const float*)d_in[16];
    const float* out2_b = (const float*)d_in[17];

    float* ws = (float*)d_ws;
    const size_t SZ = (size_t)524288 * 32;    // 16.78M floats per projection buffer
    float* AT    = ws;                         // 16384 floats
    float* in_wT = ws + 16384;                 // 1536 floats
    float* xa    = ws + 18432;                 // 67.1 MB
    float* xb    = xa + SZ;                    // 67.1 MB   (total ~134.3 MB)

    k_prep<<<70, 256, 0, stream>>>(A, in_w, AT, in_wT);
    k_pre <<<2048, 256, 0, stream>>>(X, in_w, in_b, xa, xb);

    k_fused<<<8 * T_, 256, 0, stream>>>(X, xa, xb, AT, in_wT, in_b,
                                        ct_w, ct_b, cs_w, cs_b,
                                        gcn_w, gcn_b, res_w, res_b,
                                        skip_w, skip_b,
                                        out1_w, out1_b, out2_w, out2_b,
                                        (float*)d_out);
}

// Round 8
// 241.428 us; speedup vs baseline: 105.1642x; 9.9690x over previous
//
#include <hip/hip_runtime.h>
#include <math.h>

#define T_ 512

typedef _Float16 half8 __attribute__((ext_vector_type(8)));
typedef float f32x4 __attribute__((ext_vector_type(4)));

__device__ __forceinline__ float sigm(float x)  { return 1.0f / (1.0f + __expf(-x)); }
__device__ __forceinline__ float tanhf_(float x){ return 1.0f - 2.0f / (1.0f + __expf(2.0f * x)); }

// ---------------------------------------------------------------------------
// Prep: build f16 fragment-order buffers in d_ws.
//  AF  [16384 f16]  : adjacency A frags: ((mt*4+kt)*64+L)*8+j = A[mt*16+(L&15)][kt*32+(L>>4)*8+j]
//  WF  [23552 f16]  : 23 matrices x 2 nt x 64 lanes x 8: B[k=(L>>4)*8+j][n=nt*16+(L&15)]
//     mat = l*5+{0:convT,1:convS,2:gw,3:rw,4:sw}, 20:w1, 21:w2(pad), 22:winit
//     convT/S are the folded weights [in_w@tap0 ; in_w@tap1] (K=32 stacked prev|cur)
//  BIAS[512 f32]    : per layer: beffT, bprevT, beffS, bprevS (32 each)
// ---------------------------------------------------------------------------
__global__ __launch_bounds__(256) void k_prep(
    const float* __restrict__ A,     const float* __restrict__ in_w,
    const float* __restrict__ in_b,
    const float* __restrict__ ct_w,  const float* __restrict__ ct_b,
    const float* __restrict__ cs_w,  const float* __restrict__ cs_b,
    const float* __restrict__ gcn_w, const float* __restrict__ res_w,
    const float* __restrict__ skip_w,
    const float* __restrict__ out1_w,const float* __restrict__ out2_w,
    _Float16* __restrict__ AF, _Float16* __restrict__ WF, float* __restrict__ BIAS)
{
    int idx = blockIdx.x * 256 + threadIdx.x;
    if (idx < 16384) {
        int j = idx & 7, L = (idx >> 3) & 63, tile = idx >> 9;
        int mt = tile >> 2, kt = tile & 3;
        int m = mt * 16 + (L & 15), k = kt * 32 + (L >> 4) * 8 + j;
        AF[idx] = (_Float16)A[m * 128 + k];
    } else if (idx < 39936) {
        int e = idx - 16384;
        int j = e & 7, L = (e >> 3) & 63, nt = (e >> 9) & 1, mat = e >> 10;
        int k = (L >> 4) * 8 + j, n = nt * 16 + (L & 15);
        float v = 0.f;
        if (mat < 20) {
            int l = mat / 5, r = mat - l * 5;
            if (r <= 1) {
                const float* tw = (r == 0 ? ct_w : cs_w) + l * 2048;
                int bro = r * 32;                 // in_w column block for this branch
                if (k < 16) {                     // prev tap (tap0)
                    for (int c = 0; c < 32; ++c) v += in_w[k*96 + bro + c] * tw[c*32 + n];
                } else {                          // cur tap (tap1)
                    for (int c = 0; c < 32; ++c) v += in_w[(k-16)*96 + bro + c] * tw[1024 + c*32 + n];
                }
            } else if (r == 2) v = gcn_w [l*1024 + k*32 + n];
            else if   (r == 3) v = res_w [l*1024 + k*32 + n];
            else               v = skip_w[l*1024 + k*32 + n];
        } else if (mat == 20) v = out1_w[k*32 + n];
        else if   (mat == 21) v = (n < 16) ? out2_w[k*16 + n] : 0.f;
        else                  v = (k >= 16) ? in_w[(k-16)*96 + 64 + n] : 0.f;   // winit
        WF[e] = (_Float16)v;
    } else if (idx < 40448) {
        int e = idx - 39936;
        int n = e & 31, q = (e >> 5) & 3, l = e >> 7;
        float v = 0.f;
        if (q == 0) { v = ct_b[l*32+n]; for (int c = 0; c < 32; ++c) v += in_b[c]      * ct_w[l*2048 + 1024 + c*32 + n]; }
        else if (q == 1) {              for (int c = 0; c < 32; ++c) v += in_b[c]      * ct_w[l*2048 +        c*32 + n]; }
        else if (q == 2) { v = cs_b[l*32+n]; for (int c = 0; c < 32; ++c) v += in_b[32+c] * cs_w[l*2048 + 1024 + c*32 + n]; }
        else {                          for (int c = 0; c < 32; ++c) v += in_b[32+c]   * cs_w[l*2048 +        c*32 + n]; }
        BIAS[l*128 + q*32 + n] = v;
    }
}

// ---------------------------------------------------------------------------
// Fused net, full MFMA. One block per (b,t), 4 waves; wave w owns nodes 32w..32w+31
// (M-tiles 2w, 2w+1). D-layout (HW-verified): D[m=(lane>>4)*4+reg][n=lane&15].
// A-operand: lane holds A[m=lane&15][k=(lane>>4)*8+j]; B: B[k same][n=lane&15].
// fp32 master xres/skip in D-layout registers; f16 only on MFMA operands.
// TWO coordinate systems: conv path reads X at (b*128+node)*512+t (raw reshape);
// xres init reads X at btid*128+node (true [B,T,N,F] coords)  <-- round-3/7 bug.
// ---------------------------------------------------------------------------
__global__ __launch_bounds__(256, 3) void k_fused(
    const float* __restrict__ X,
    const _Float16* __restrict__ AF,
    const _Float16* __restrict__ WF,
    const float* __restrict__ BIAS,
    const float* __restrict__ in_b,
    const float* __restrict__ gcn_b,
    const float* __restrict__ res_b,
    const float* __restrict__ skip_b,
    const float* __restrict__ b1,
    const float* __restrict__ b2,
    float* __restrict__ out)
{
    __shared__ _Float16 Pld [128 * 40];      // [node][prev16|cur16 + pad8]
    __shared__ _Float16 hsld[128 * 40];      // node-major D->A transform buffer
    __shared__ _Float16 xsT [2][32 * 136];   // channel-major xres (ping-pong)

    const int btid = blockIdx.x;
    const int b = btid >> 9, t = btid & (T_ - 1);
    const int tid = threadIdx.x, lane = tid & 63, w = tid >> 6;
    const int lm = lane & 15, kb = lane >> 4;
    const int R = w * 32;

    const half8* AFv = (const half8*)AF;
    const half8* WFv = (const half8*)WF;
    const f32x4 zero4 = {0.f, 0.f, 0.f, 0.f};

    // persistent adjacency frags (L2-hot coalesced b128 loads)
    half8 Af[2][4];
#pragma unroll
    for (int mt = 0; mt < 2; ++mt)
#pragma unroll
        for (int kt = 0; kt < 4; ++kt)
            Af[mt][kt] = AFv[((w * 2 + mt) * 4 + kt) * 64 + lane];

    float xm[2][2][4];                       // fp32 xres master, D-layout
    float sk[2][2][4];                       // fp32 skip accumulator, D-layout
#pragma unroll
    for (int mt = 0; mt < 2; ++mt)
#pragma unroll
        for (int nt = 0; nt < 2; ++nt)
#pragma unroll
            for (int r = 0; r < 4; ++r) sk[mt][nt][r] = 0.f;

    // ---- xres init from TRUE-coordinate X rows: xm = Xtrue @ in_w[:,64:96] + in_b[64:96] ----
    {
        int row = R + (lane >> 1);
        int cur = lane & 1;
        half8 h0 = {0,0,0,0,0,0,0,0}, h1 = {0,0,0,0,0,0,0,0};
        if (cur) {    // k-slots [16,32): the true X row; k<16 slots stay zero (winit weights zero there)
            const float4* s4 = (const float4*)(X + ((size_t)btid * 128 + row) * 16);
            float v[16];
#pragma unroll
            for (int k = 0; k < 4; ++k) {
                float4 u = s4[k];
                v[4*k+0] = u.x; v[4*k+1] = u.y; v[4*k+2] = u.z; v[4*k+3] = u.w;
            }
#pragma unroll
            for (int k = 0; k < 8; ++k) { h0[k] = (_Float16)v[k]; h1[k] = (_Float16)v[8 + k]; }
        }
        *(half8*)&hsld[row * 40 + cur * 16]     = h0;
        *(half8*)&hsld[row * 40 + cur * 16 + 8] = h1;
    }
    __syncthreads();
    {
        half8 pt[2];
#pragma unroll
        for (int mt = 0; mt < 2; ++mt)
            pt[mt] = *(const half8*)&hsld[(R + mt * 16 + lm) * 40 + kb * 8];
#pragma unroll
        for (int nt = 0; nt < 2; ++nt) {
            half8 wi = WFv[(22 * 2 + nt) * 64 + lane];
            float bi = in_b[64 + nt * 16 + lm];
#pragma unroll
            for (int mt = 0; mt < 2; ++mt) {
                f32x4 di = __builtin_amdgcn_mfma_f32_16x16x32_f16(pt[mt], wi, zero4, 0, 0, 0);
#pragma unroll
                for (int r = 0; r < 4; ++r) xm[mt][nt][r] = di[r] + bi;
            }
        }
    }
    __syncthreads();   // all hsld reads done before any later overwrite

#pragma unroll 1
    for (int l = 0; l < 4; ++l) {
        const int d = 1 << l;
        const bool pv = (t >= d);            // block-uniform

        // ---- stage P = [X_prev | X_cur] f16 (conv coords, wave-local rows) ----
        {
            int row = R + (lane >> 1);
            int cur = lane & 1;
            size_t q = (size_t)(b * 128 + row) * T_ + t - (cur ? 0 : d);
            float v[16];
            if (cur || pv) {
                const float4* s4 = (const float4*)(X + q * 16);
#pragma unroll
                for (int k = 0; k < 4; ++k) {
                    float4 u = s4[k];
                    v[4*k+0] = u.x; v[4*k+1] = u.y; v[4*k+2] = u.z; v[4*k+3] = u.w;
                }
            } else {
#pragma unroll
                for (int k = 0; k < 16; ++k) v[k] = 0.f;
            }
            half8 h0, h1;
#pragma unroll
            for (int k = 0; k < 8; ++k) { h0[k] = (_Float16)v[k]; h1[k] = (_Float16)v[8 + k]; }
            *(half8*)&Pld[row * 40 + cur * 16]     = h0;
            *(half8*)&Pld[row * 40 + cur * 16 + 8] = h1;
        }
        __syncthreads();   // B0: P staged

        // ---- conv (both branches share P A-frags), K=32 folded proj ----
        half8 pf[2];
#pragma unroll
        for (int mt = 0; mt < 2; ++mt)
            pf[mt] = *(const half8*)&Pld[(R + mt * 16 + lm) * 40 + kb * 8];

        f32x4 Dt[2][2], Ds[2][2];
#pragma unroll
        for (int nt = 0; nt < 2; ++nt) {
            half8 wt = WFv[((l * 5 + 0) * 2 + nt) * 64 + lane];
            half8 ws = WFv[((l * 5 + 1) * 2 + nt) * 64 + lane];
#pragma unroll
            for (int mt = 0; mt < 2; ++mt) {
                Dt[mt][nt] = __builtin_amdgcn_mfma_f32_16x16x32_f16(pf[mt], wt, zero4, 0, 0, 0);
                Ds[mt][nt] = __builtin_amdgcn_mfma_f32_16x16x32_f16(pf[mt], ws, zero4, 0, 0, 0);
            }
        }
        float tc[2][2][4];
#pragma unroll
        for (int nt = 0; nt < 2; ++nt) {
            int n = nt * 16 + lm;
            float bt = BIAS[l*128 +      n] + (pv ? BIAS[l*128 + 32 + n] : 0.f);
            float bs = BIAS[l*128 + 64 + n] + (pv ? BIAS[l*128 + 96 + n] : 0.f);
#pragma unroll
            for (int mt = 0; mt < 2; ++mt)
#pragma unroll
                for (int r = 0; r < 4; ++r)
                    tc[mt][nt][r] = tanhf_(Dt[mt][nt][r] + bt) * sigm(Ds[mt][nt][r] + bs);
        }

        // ---- publish xres state (f16, channel-major) ----
        {
            _Float16* xp = xsT[l & 1];
#pragma unroll
            for (int mt = 0; mt < 2; ++mt)
#pragma unroll
                for (int nt = 0; nt < 2; ++nt)
#pragma unroll
                    for (int r = 0; r < 4; ++r)
                        xp[(nt * 16 + lm) * 136 + R + mt * 16 + kb * 4 + r] =
                            (_Float16)xm[mt][nt][r];
        }
        __syncthreads();   // B1: xsT ready (cross-wave)

        // ---- A-mix: Ax = A @ xs  (K = 128 nodes) ----
        f32x4 AxD[2][2];
#pragma unroll
        for (int nt = 0; nt < 2; ++nt) {
            half8 Bx[4];
#pragma unroll
            for (int kt = 0; kt < 4; ++kt)
                Bx[kt] = *(const half8*)&xsT[l & 1][(nt * 16 + lm) * 136 + kt * 32 + kb * 8];
#pragma unroll
            for (int mt = 0; mt < 2; ++mt) {
                f32x4 acc = zero4;
#pragma unroll
                for (int kt = 0; kt < 4; ++kt)
                    acc = __builtin_amdgcn_mfma_f32_16x16x32_f16(Af[mt][kt], Bx[kt], acc, 0, 0, 0);
                AxD[mt][nt] = acc;
            }
        }
        // D -> node-major LDS (wave-local rows)
#pragma unroll
        for (int mt = 0; mt < 2; ++mt)
#pragma unroll
            for (int nt = 0; nt < 2; ++nt)
#pragma unroll
                for (int r = 0; r < 4; ++r)
                    hsld[(R + mt * 16 + kb * 4 + r) * 40 + nt * 16 + lm] =
                        (_Float16)AxD[mt][nt][r];
        __syncthreads();   // B2: Ax transform visible

        // ---- gcn = Ax @ gw + gb ; h = gcn + tc ----
        half8 ha[2];
#pragma unroll
        for (int mt = 0; mt < 2; ++mt)
            ha[mt] = *(const half8*)&hsld[(R + mt * 16 + lm) * 40 + kb * 8];
        f32x4 hD[2][2];
#pragma unroll
        for (int nt = 0; nt < 2; ++nt) {
            half8 wg = WFv[((l * 5 + 2) * 2 + nt) * 64 + lane];
            float gb = gcn_b[l * 32 + nt * 16 + lm];
#pragma unroll
            for (int mt = 0; mt < 2; ++mt) {
                f32x4 acc = __builtin_amdgcn_mfma_f32_16x16x32_f16(ha[mt], wg, zero4, 0, 0, 0);
#pragma unroll
                for (int r = 0; r < 4; ++r) hD[mt][nt][r] = acc[r] + gb + tc[mt][nt][r];
            }
        }
        __syncthreads();   // B2.5: all ha reads done before overwrite
#pragma unroll
        for (int mt = 0; mt < 2; ++mt)
#pragma unroll
            for (int nt = 0; nt < 2; ++nt)
#pragma unroll
                for (int r = 0; r < 4; ++r)
                    hsld[(R + mt * 16 + kb * 4 + r) * 40 + nt * 16 + lm] =
                        (_Float16)hD[mt][nt][r];
        __syncthreads();   // B3: h transform visible

        // ---- res & skip mixes ----
        half8 hh[2];
#pragma unroll
        for (int mt = 0; mt < 2; ++mt)
            hh[mt] = *(const half8*)&hsld[(R + mt * 16 + lm) * 40 + kb * 8];
#pragma unroll
        for (int nt = 0; nt < 2; ++nt) {
            half8 wr = WFv[((l * 5 + 3) * 2 + nt) * 64 + lane];
            half8 wsk= WFv[((l * 5 + 4) * 2 + nt) * 64 + lane];
            float rb = res_b [l * 32 + nt * 16 + lm];
            float sb = skip_b[l * 32 + nt * 16 + lm];
#pragma unroll
            for (int mt = 0; mt < 2; ++mt) {
                f32x4 rD = __builtin_amdgcn_mfma_f32_16x16x32_f16(hh[mt], wr,  zero4, 0, 0, 0);
                f32x4 sD = __builtin_amdgcn_mfma_f32_16x16x32_f16(hh[mt], wsk, zero4, 0, 0, 0);
#pragma unroll
                for (int r = 0; r < 4; ++r) {
                    xm[mt][nt][r] += rD[r] + rb;
                    sk[mt][nt][r] += sD[r] + sb;
                }
            }
        }
    }

    // ---- output head ----
    __syncthreads();   // protect last hh reads
#pragma unroll
    for (int mt = 0; mt < 2; ++mt)
#pragma unroll
        for (int nt = 0; nt < 2; ++nt)
#pragma unroll
            for (int r = 0; r < 4; ++r)
                hsld[(R + mt * 16 + kb * 4 + r) * 40 + nt * 16 + lm] =
                    (_Float16)fmaxf(sk[mt][nt][r], 0.f);
    __syncthreads();

    half8 sf[2];
#pragma unroll
    for (int mt = 0; mt < 2; ++mt)
        sf[mt] = *(const half8*)&hsld[(R + mt * 16 + lm) * 40 + kb * 8];
    f32x4 h1D[2][2];
#pragma unroll
    for (int nt = 0; nt < 2; ++nt) {
        half8 w1f = WFv[(20 * 2 + nt) * 64 + lane];
        float bb = b1[nt * 16 + lm];
#pragma unroll
        for (int mt = 0; mt < 2; ++mt) {
            f32x4 acc = __builtin_amdgcn_mfma_f32_16x16x32_f16(sf[mt], w1f, zero4, 0, 0, 0);
#pragma unroll
            for (int r = 0; r < 4; ++r) h1D[mt][nt][r] = fmaxf(acc[r] + bb, 0.f);
        }
    }
    __syncthreads();
#pragma unroll
    for (int mt = 0; mt < 2; ++mt)
#pragma unroll
        for (int nt = 0; nt < 2; ++nt)
#pragma unroll
            for (int r = 0; r < 4; ++r)
                hsld[(R + mt * 16 + kb * 4 + r) * 40 + nt * 16 + lm] =
                    (_Float16)h1D[mt][nt][r];
    __syncthreads();

    half8 hf[2];
#pragma unroll
    for (int mt = 0; mt < 2; ++mt)
        hf[mt] = *(const half8*)&hsld[(R + mt * 16 + lm) * 40 + kb * 8];
    {
        half8 w2f = WFv[(21 * 2 + 0) * 64 + lane];
        float bb = b2[lm];
#pragma unroll
        for (int mt = 0; mt < 2; ++mt) {
            f32x4 o = __builtin_amdgcn_mfma_f32_16x16x32_f16(hf[mt], w2f, zero4, 0, 0, 0);
#pragma unroll
            for (int r = 0; r < 4; ++r)
                out[((size_t)btid * 128 + R + mt * 16 + kb * 4 + r) * 16 + lm] = o[r] + bb;
        }
    }
}

// ---------------------------------------------------------------------------
extern "C" void kernel_launch(void* const* d_in, const int* in_sizes, int n_in,
                              void* d_out, int out_size, void* d_ws, size_t ws_size,
                              hipStream_t stream)
{
    const float* X      = (const float*)d_in[0];
    const float* A      = (const float*)d_in[1];
    const float* in_w   = (const float*)d_in[2];
    const float* in_b   = (const float*)d_in[3];
    const float* ct_w   = (const float*)d_in[4];
    const float* ct_b   = (const float*)d_in[5];
    const float* cs_w   = (const float*)d_in[6];
    const float* cs_b   = (const float*)d_in[7];
    const float* gcn_w  = (const float*)d_in[8];
    const float* gcn_b  = (const float*)d_in[9];
    const float* res_w  = (const float*)d_in[10];
    const float* res_b  = (const float*)d_in[11];
    const float* skip_w = (const float*)d_in[12];
    const float* skip_b = (const float*)d_in[13];
    const float* out1_w = (const float*)d_in[14];
    const float* out1_b = (const float*)d_in[15];
    const float* out2_w = (const float*)d_in[16];
    const float* out2_b = (const float*)d_in[17];

    char* ws = (char*)d_ws;
    _Float16* AF   = (_Float16*)ws;             // 16384 f16 = 32768 B
    _Float16* WF   = (_Float16*)(ws + 32768);   // 23552 f16 = 47104 B
    float*    BIAS = (float*)   (ws + 32768 + 47104);   // 512 f32

    k_prep<<<158, 256, 0, stream>>>(A, in_w, in_b, ct_w, ct_b, cs_w, cs_b,
                                    gcn_w, res_w, skip_w, out1_w, out2_w,
                                    AF, WF, BIAS);

    k_fused<<<8 * T_, 256, 0, stream>>>(X, AF, WF, BIAS, in_b,
                                        gcn_b, res_b, skip_b,
                                        out1_b, out2_b, (float*)d_out);
}

// Round 9
// 237.223 us; speedup vs baseline: 107.0286x; 1.0177x over previous
//
#include <hip/hip_runtime.h>
#include <math.h>

#define T_ 512

typedef _Float16 half8 __attribute__((ext_vector_type(8)));
typedef _Float16 half4 __attribute__((ext_vector_type(4)));
typedef float f32x4 __attribute__((ext_vector_type(4)));

__device__ __forceinline__ float sigm(float x)  { return 1.0f / (1.0f + __expf(-x)); }
__device__ __forceinline__ float tanhf_(float x){ return 1.0f - 2.0f / (1.0f + __expf(2.0f * x)); }

__device__ __forceinline__ half4 pack4(f32x4 v) {
    half4 h;
    h[0] = (_Float16)v[0]; h[1] = (_Float16)v[1];
    h[2] = (_Float16)v[2]; h[3] = (_Float16)v[3];
    return h;
}

// ---------------------------------------------------------------------------
// Prep fragment buffers in d_ws (all W[k][col] generic form; A-frag and B-frag
// share the same (lane,slot)->(row,col) map, so one layout serves both roles).
//  AF  [16384 f16] : adjacency, frag((it*4+kt))[lane][j] = A[it*16+(L&15)][kt*32+(L>>4)*8+j]
//  W32 [ 9216 f16] : K=32 mats: 0..7 = folded conv (l*2+branch), 8 = winit
//                    frag idx (mat*2+ct)*64+L, slot j: W[k=(L>>4)*8+j][ct*16+(L&15)]
//  W16 [14336 f16] : K=16 mats: l*3+{0:gw,1:rw,2:sw} (0..11), 12:w1, 13:w2(pad)
//                    frag idx (mat*4+ks*2+ct)*64+L, slot i: W[ks*16+(L>>4)*4+i][ct*16+(L&15)]
//  BIAS[512 f32]   : per layer: beffT, bprevT, beffS, bprevS (32 each)
// total idx = 16384+9216+14336+512 = 40448 = 158*256
// ---------------------------------------------------------------------------
__global__ __launch_bounds__(256) void k_prep(
    const float* __restrict__ A,     const float* __restrict__ in_w,
    const float* __restrict__ in_b,
    const float* __restrict__ ct_w,  const float* __restrict__ ct_b,
    const float* __restrict__ cs_w,  const float* __restrict__ cs_b,
    const float* __restrict__ gcn_w, const float* __restrict__ res_w,
    const float* __restrict__ skip_w,
    const float* __restrict__ out1_w,const float* __restrict__ out2_w,
    _Float16* __restrict__ FR, float* __restrict__ BIAS)
{
    int idx = blockIdx.x * 256 + threadIdx.x;
    if (idx < 16384) {
        int j = idx & 7, L = (idx >> 3) & 63, tile = idx >> 9;
        int it = tile >> 2, kt = tile & 3;
        FR[idx] = (_Float16)A[(it * 16 + (L & 15)) * 128 + kt * 32 + (L >> 4) * 8 + j];
    } else if (idx < 25600) {
        int e = idx - 16384;
        int j = e & 7, L = (e >> 3) & 63, ct = (e >> 9) & 1, mat = e >> 10;
        int k = (L >> 4) * 8 + j, col = ct * 16 + (L & 15);
        float v = 0.f;
        if (mat < 8) {
            int l = mat >> 1, br = mat & 1;
            const float* tw = (br ? cs_w : ct_w) + l * 2048;
            int bro = br * 32;
            if (k < 16) { for (int c = 0; c < 32; ++c) v += in_w[k*96 + bro + c] * tw[c*32 + col]; }
            else        { for (int c = 0; c < 32; ++c) v += in_w[(k-16)*96 + bro + c] * tw[1024 + c*32 + col]; }
        } else {
            v = (k >= 16) ? in_w[(k - 16) * 96 + 64 + col] : 0.f;   // winit
        }
        FR[idx] = (_Float16)v;
    } else if (idx < 39936) {
        int e = idx - 25600;
        int i = e & 3, L = (e >> 2) & 63, ct = (e >> 8) & 1, ks = (e >> 9) & 1, mat = e >> 10;
        int k = ks * 16 + (L >> 4) * 4 + i, col = ct * 16 + (L & 15);
        float v;
        if (mat < 12) {
            int l = mat / 3, r = mat - l * 3;
            const float* W = (r == 0) ? gcn_w : (r == 1) ? res_w : skip_w;
            v = W[l * 1024 + k * 32 + col];
        } else if (mat == 12) v = out1_w[k * 32 + col];
        else                  v = (ct == 0) ? out2_w[k * 16 + (L & 15)] : 0.f;
        FR[idx] = (_Float16)v;
    } else if (idx < 40448) {
        int e = idx - 39936;
        int n = e & 31, q = (e >> 5) & 3, l = e >> 7;
        float v = 0.f;
        if (q == 0) { v = ct_b[l*32+n]; for (int c = 0; c < 32; ++c) v += in_b[c]    * ct_w[l*2048 + 1024 + c*32 + n]; }
        else if (q == 1) {              for (int c = 0; c < 32; ++c) v += in_b[c]    * ct_w[l*2048 +        c*32 + n]; }
        else if (q == 2) { v = cs_b[l*32+n]; for (int c = 0; c < 32; ++c) v += in_b[32+c] * cs_w[l*2048 + 1024 + c*32 + n]; }
        else {                          for (int c = 0; c < 32; ++c) v += in_b[32+c] * cs_w[l*2048 +        c*32 + n]; }
        BIAS[l*128 + q*32 + n] = v;
    }
}

// ---------------------------------------------------------------------------
// Fused net, MFMA with K=16 register chaining (D==B-frag; D fed to A == D^T).
// One block per (b,t), 4 waves; wave w owns node-tiles {2w, 2w+1}.
// Orientation alternates: xres/res normal [node][c]; conv/Ax/h/skip/head
// transposed [c][node]. Only per-layer LDS: P staging (wave-local, no barrier)
// and the xres publish for the cross-wave A-mix (1 barrier/layer).
// ---------------------------------------------------------------------------
__global__ __launch_bounds__(256, 3) void k_fused(
    const float* __restrict__ X,
    const _Float16* __restrict__ FR,
    const float* __restrict__ BIAS,
    const float* __restrict__ in_b,
    const float* __restrict__ gcn_b,
    const float* __restrict__ res_b,
    const float* __restrict__ skip_b,
    const float* __restrict__ b1,
    const float* __restrict__ b2,
    float* __restrict__ out)
{
    __shared__ _Float16 Pld[128 * 40];        // [node][prev16|cur16|pad8]
    __shared__ _Float16 xsT[2][32 * 136];     // [chan][node(128)+pad8], ping-pong

    const int btid = blockIdx.x;
    const int b = btid >> 9, t = btid & (T_ - 1);
    const int tid = threadIdx.x, lane = tid & 63, w = tid >> 6;
    const int lm = lane & 15, kb = lane >> 4;
    const int R = w * 32;

    const half8* AFv  = (const half8*)FR;                 // adjacency frags
    const half8* W32v = (const half8*)(FR + 16384);
    const half4* W16v = (const half4*)(FR + 25600);
    const f32x4 zero4 = {0.f, 0.f, 0.f, 0.f};

    const int row = lane >> 1, ch = lane & 1;             // staging roles

    // ---- stage TRUE-coordinate X rows (cur slab), zeros in prev slab ----
    {
        const float4* s4 = (const float4*)(X + ((size_t)btid * 128 + R + row) * 16 + ch * 8);
        float4 u0 = s4[0], u1 = s4[1];
        half8 hv;
        hv[0]=(_Float16)u0.x; hv[1]=(_Float16)u0.y; hv[2]=(_Float16)u0.z; hv[3]=(_Float16)u0.w;
        hv[4]=(_Float16)u1.x; hv[5]=(_Float16)u1.y; hv[6]=(_Float16)u1.z; hv[7]=(_Float16)u1.w;
        half8 z8 = {0,0,0,0,0,0,0,0};
        *(half8*)&Pld[(R + row) * 40 + ch * 8]      = z8;
        *(half8*)&Pld[(R + row) * 40 + 16 + ch * 8] = hv;
    }

    // ---- xres init (normal [node][c]): A = Ptrue frag, B = winit ----
    f32x4 xm[2][2], skT[2][2];
    {
        half8 pt0 = *(const half8*)&Pld[(R + lm) * 40 + kb * 8];
        half8 pt1 = *(const half8*)&Pld[(R + 16 + lm) * 40 + kb * 8];
#pragma unroll
        for (int f = 0; f < 2; ++f) {
            half8 wi = W32v[(8 * 2 + f) * 64 + lane];
            float bi = in_b[64 + f * 16 + lm];
            f32x4 d0 = __builtin_amdgcn_mfma_f32_16x16x32_f16(pt0, wi, zero4, 0, 0, 0);
            f32x4 d1 = __builtin_amdgcn_mfma_f32_16x16x32_f16(pt1, wi, zero4, 0, 0, 0);
#pragma unroll
            for (int r = 0; r < 4; ++r) { xm[0][f][r] = d0[r] + bi; xm[1][f][r] = d1[r] + bi; }
        }
#pragma unroll
        for (int a = 0; a < 2; ++a)
#pragma unroll
            for (int c = 0; c < 2; ++c) skT[a][c] = zero4;
    }

    // ---- restage cur slab with CONV-coordinate rows ----
    {
        const float4* s4 = (const float4*)(X + ((size_t)(b * 128 + R + row) * T_ + t) * 16 + ch * 8);
        float4 u0 = s4[0], u1 = s4[1];
        half8 hv;
        hv[0]=(_Float16)u0.x; hv[1]=(_Float16)u0.y; hv[2]=(_Float16)u0.z; hv[3]=(_Float16)u0.w;
        hv[4]=(_Float16)u1.x; hv[5]=(_Float16)u1.y; hv[6]=(_Float16)u1.z; hv[7]=(_Float16)u1.w;
        *(half8*)&Pld[(R + row) * 40 + 16 + ch * 8] = hv;
    }

#pragma unroll 1
    for (int l = 0; l < 4; ++l) {
        const int d = 1 << l;
        const bool pv = (t >= d);                 // block-uniform

        // ---- stage prev slab (conv coords), zeros if t<d ----
        {
            half8 hv = {0,0,0,0,0,0,0,0};
            if (pv) {
                const float4* s4 = (const float4*)(X + ((size_t)(b * 128 + R + row) * T_ + (t - d)) * 16 + ch * 8);
                float4 u0 = s4[0], u1 = s4[1];
                hv[0]=(_Float16)u0.x; hv[1]=(_Float16)u0.y; hv[2]=(_Float16)u0.z; hv[3]=(_Float16)u0.w;
                hv[4]=(_Float16)u1.x; hv[5]=(_Float16)u1.y; hv[6]=(_Float16)u1.z; hv[7]=(_Float16)u1.w;
            }
            *(half8*)&Pld[(R + row) * 40 + ch * 8] = hv;
        }

        // ---- conv (transposed [c_out][node]): A = Wfold frag, B = P frag ----
        half8 pf0 = *(const half8*)&Pld[(R + lm) * 40 + kb * 8];
        half8 pf1 = *(const half8*)&Pld[(R + 16 + lm) * 40 + kb * 8];
        f32x4 tcv[2][2];                          // [ct][mt]
#pragma unroll
        for (int ct = 0; ct < 2; ++ct) {
            half8 wt = W32v[((l * 2 + 0) * 2 + ct) * 64 + lane];
            half8 ws = W32v[((l * 2 + 1) * 2 + ct) * 64 + lane];
            f32x4 dt0 = __builtin_amdgcn_mfma_f32_16x16x32_f16(wt, pf0, zero4, 0, 0, 0);
            f32x4 dt1 = __builtin_amdgcn_mfma_f32_16x16x32_f16(wt, pf1, zero4, 0, 0, 0);
            f32x4 ds0 = __builtin_amdgcn_mfma_f32_16x16x32_f16(ws, pf0, zero4, 0, 0, 0);
            f32x4 ds1 = __builtin_amdgcn_mfma_f32_16x16x32_f16(ws, pf1, zero4, 0, 0, 0);
            const float4 bt0 = *(const float4*)&BIAS[l*128 +       ct*16 + kb*4];
            const float4 bt1 = *(const float4*)&BIAS[l*128 + 32 +  ct*16 + kb*4];
            const float4 bs0 = *(const float4*)&BIAS[l*128 + 64 +  ct*16 + kb*4];
            const float4 bs1 = *(const float4*)&BIAS[l*128 + 96 +  ct*16 + kb*4];
            float btq[4] = { bt0.x + (pv ? bt1.x : 0.f), bt0.y + (pv ? bt1.y : 0.f),
                             bt0.z + (pv ? bt1.z : 0.f), bt0.w + (pv ? bt1.w : 0.f) };
            float bsq[4] = { bs0.x + (pv ? bs1.x : 0.f), bs0.y + (pv ? bs1.y : 0.f),
                             bs0.z + (pv ? bs1.z : 0.f), bs0.w + (pv ? bs1.w : 0.f) };
#pragma unroll
            for (int r = 0; r < 4; ++r) {
                tcv[ct][0][r] = tanhf_(dt0[r] + btq[r]) * sigm(ds0[r] + bsq[r]);
                tcv[ct][1][r] = tanhf_(dt1[r] + btq[r]) * sigm(ds1[r] + bsq[r]);
            }
        }

        // ---- publish xres (normal D -> chan-major LDS, b64 packed) ----
        const int buf = l & 1;
#pragma unroll
        for (int mt = 0; mt < 2; ++mt)
#pragma unroll
            for (int f = 0; f < 2; ++f)
                *(half4*)&xsT[buf][(f * 16 + lm) * 136 + R + mt * 16 + kb * 4] = pack4(xm[mt][f]);
        __syncthreads();

        // ---- A-mix: AxT[c][i] — A = xres^T frags (LDS), B = adjacency frags ----
        f32x4 AxT[2][2];                          // [f][mt]
        half8 Afr[2][4];
#pragma unroll
        for (int mt = 0; mt < 2; ++mt)
#pragma unroll
            for (int kt = 0; kt < 4; ++kt)
                Afr[mt][kt] = AFv[((w * 2 + mt) * 4 + kt) * 64 + lane];
#pragma unroll
        for (int f = 0; f < 2; ++f) {
            half8 xa[4];
#pragma unroll
            for (int kt = 0; kt < 4; ++kt)
                xa[kt] = *(const half8*)&xsT[buf][(f * 16 + lm) * 136 + kt * 32 + kb * 8];
#pragma unroll
            for (int mt = 0; mt < 2; ++mt) {
                f32x4 acc = zero4;
#pragma unroll
                for (int kt = 0; kt < 4; ++kt)
                    acc = __builtin_amdgcn_mfma_f32_16x16x32_f16(xa[kt], Afr[mt][kt], acc, 0, 0, 0);
                AxT[f][mt] = acc;
            }
        }

        // ---- gcn_T: A = gw frag (W^T semantics), B = AxT register-direct ----
        half4 axh[2][2];
#pragma unroll
        for (int f = 0; f < 2; ++f)
#pragma unroll
            for (int mt = 0; mt < 2; ++mt) axh[f][mt] = pack4(AxT[f][mt]);
        half4 hh[2][2];                           // h_T packed [g][mt]
#pragma unroll
        for (int g = 0; g < 2; ++g) {
            half4 gw0 = W16v[((l * 3 + 0) * 4 + 0 * 2 + g) * 64 + lane];
            half4 gw1 = W16v[((l * 3 + 0) * 4 + 1 * 2 + g) * 64 + lane];
            const float4 gb = *(const float4*)&gcn_b[l * 32 + g * 16 + kb * 4];
            float gbq[4] = { gb.x, gb.y, gb.z, gb.w };
#pragma unroll
            for (int mt = 0; mt < 2; ++mt) {
                f32x4 acc = __builtin_amdgcn_mfma_f32_16x16x16f16(gw0, axh[0][mt], zero4, 0, 0, 0);
                acc = __builtin_amdgcn_mfma_f32_16x16x16f16(gw1, axh[1][mt], acc, 0, 0, 0);
#pragma unroll
                for (int r = 0; r < 4; ++r) acc[r] += gbq[r] + tcv[g][mt][r];
                hh[g][mt] = pack4(acc);
            }
        }

        // ---- res (normal, A = h_T direct) & skip_T (B = h_T direct) ----
#pragma unroll
        for (int mt = 0; mt < 2; ++mt)
#pragma unroll
            for (int f3 = 0; f3 < 2; ++f3) {
                half4 rw0 = W16v[((l * 3 + 1) * 4 + 0 * 2 + f3) * 64 + lane];
                half4 rw1 = W16v[((l * 3 + 1) * 4 + 1 * 2 + f3) * 64 + lane];
                f32x4 acc = __builtin_amdgcn_mfma_f32_16x16x16f16(hh[0][mt], rw0, xm[mt][f3], 0, 0, 0);
                xm[mt][f3] = __builtin_amdgcn_mfma_f32_16x16x16f16(hh[1][mt], rw1, acc, 0, 0, 0);
                float rb = res_b[l * 32 + f3 * 16 + lm];
#pragma unroll
                for (int r = 0; r < 4; ++r) xm[mt][f3][r] += rb;

                half4 sw0 = W16v[((l * 3 + 2) * 4 + 0 * 2 + f3) * 64 + lane];
                half4 sw1 = W16v[((l * 3 + 2) * 4 + 1 * 2 + f3) * 64 + lane];
                f32x4 acs = __builtin_amdgcn_mfma_f32_16x16x16f16(sw0, hh[0][mt], skT[f3][mt], 0, 0, 0);
                skT[f3][mt] = __builtin_amdgcn_mfma_f32_16x16x16f16(sw1, hh[1][mt], acs, 0, 0, 0);
                const float4 sb = *(const float4*)&skip_b[l * 32 + f3 * 16 + kb * 4];
                skT[f3][mt][0] += sb.x; skT[f3][mt][1] += sb.y;
                skT[f3][mt][2] += sb.z; skT[f3][mt][3] += sb.w;
            }
    }

    // ---- output head (all register-chained, zero LDS) ----
    half4 rs[2][2];
#pragma unroll
    for (int g = 0; g < 2; ++g)
#pragma unroll
        for (int mt = 0; mt < 2; ++mt) {
            f32x4 v;
#pragma unroll
            for (int r = 0; r < 4; ++r) v[r] = fmaxf(skT[g][mt][r], 0.f);
            rs[g][mt] = pack4(v);
        }
    half4 h1h[2][2];
#pragma unroll
    for (int g4 = 0; g4 < 2; ++g4) {
        half4 w10 = W16v[(12 * 4 + 0 * 2 + g4) * 64 + lane];
        half4 w11 = W16v[(12 * 4 + 1 * 2 + g4) * 64 + lane];
        const float4 bb = *(const float4*)&b1[g4 * 16 + kb * 4];
        float bbq[4] = { bb.x, bb.y, bb.z, bb.w };
#pragma unroll
        for (int mt = 0; mt < 2; ++mt) {
            f32x4 acc = __builtin_amdgcn_mfma_f32_16x16x16f16(w10, rs[0][mt], zero4, 0, 0, 0);
            acc = __builtin_amdgcn_mfma_f32_16x16x16f16(w11, rs[1][mt], acc, 0, 0, 0);
            f32x4 v;
#pragma unroll
            for (int r = 0; r < 4; ++r) v[r] = fmaxf(acc[r] + bbq[r], 0.f);
            h1h[g4][mt] = pack4(v);
        }
    }
    {
        half4 w20 = W16v[(13 * 4 + 0 * 2 + 0) * 64 + lane];
        half4 w21 = W16v[(13 * 4 + 1 * 2 + 0) * 64 + lane];
        const float4 bb = *(const float4*)&b2[kb * 4];
#pragma unroll
        for (int mt = 0; mt < 2; ++mt) {
            f32x4 acc = __builtin_amdgcn_mfma_f32_16x16x16f16(w20, h1h[0][mt], zero4, 0, 0, 0);
            acc = __builtin_amdgcn_mfma_f32_16x16x16f16(w21, h1h[1][mt], acc, 0, 0, 0);
            float4 o = make_float4(acc[0] + bb.x, acc[1] + bb.y, acc[2] + bb.z, acc[3] + bb.w);
            *(float4*)&out[((size_t)btid * 128 + R + mt * 16 + lm) * 16 + kb * 4] = o;
        }
    }
}

// ---------------------------------------------------------------------------
extern "C" void kernel_launch(void* const* d_in, const int* in_sizes, int n_in,
                              void* d_out, int out_size, void* d_ws, size_t ws_size,
                              hipStream_t stream)
{
    const float* X      = (const float*)d_in[0];
    const float* A      = (const float*)d_in[1];
    const float* in_w   = (const float*)d_in[2];
    const float* in_b   = (const float*)d_in[3];
    const float* ct_w   = (const float*)d_in[4];
    const float* ct_b   = (const float*)d_in[5];
    const float* cs_w   = (const float*)d_in[6];
    const float* cs_b   = (const float*)d_in[7];
    const float* gcn_w  = (const float*)d_in[8];
    const float* gcn_b  = (const float*)d_in[9];
    const float* res_w  = (const float*)d_in[10];
    const float* res_b  = (const float*)d_in[11];
    const float* skip_w = (const float*)d_in[12];
    const float* skip_b = (const float*)d_in[13];
    const float* out1_w = (const float*)d_in[14];
    const float* out1_b = (const float*)d_in[15];
    const float* out2_w = (const float*)d_in[16];
    const float* out2_b = (const float*)d_in[17];

    _Float16* FR   = (_Float16*)d_ws;                 // 39936 f16 = 79872 B
    float*    BIAS = (float*)((char*)d_ws + 79872);   // 512 f32

    k_prep<<<158, 256, 0, stream>>>(A, in_w, in_b, ct_w, ct_b, cs_w, cs_b,
                                    gcn_w, res_w, skip_w, out1_w, out2_w,
                                    FR, BIAS);

    k_fused<<<8 * T_, 256, 0, stream>>>(X, FR, BIAS, in_b,
                                        gcn_b, res_b, skip_b,
                                        out1_b, out2_b, (float*)d_out);
}